// Round 17
// baseline (677.589 us; speedup 1.0000x reference)
//
#include <hip/hip_runtime.h>
#include <hip/hip_fp16.h>

#define NN    20000
#define NE    150000
#define HD    256
#define NT    4
#define NR    8
#define NH    8
#define DKq   32
#define NL    2
#define MAXL  240
#define HBLK  256
#define SCB   ((NN + 255)/256)
#define TMAX  1260
#define FOLDN 79
#define FOLDC 15
#define INV_SQRT_DK 0.17677669529663687f

typedef _Float16 f16x4 __attribute__((ext_vector_type(4)));
typedef float    f32x4v __attribute__((ext_vector_type(4)));

// ---------- node bucketing (by type) + compact 16-row tile list ----------
__global__ __launch_bounds__(256) void k_nhist(const int* __restrict__ ntype, int* __restrict__ nhist)
{
    __shared__ int h[NT];
    const int tid = threadIdx.x, b = blockIdx.x;
    if (tid < NT) h[tid] = 0;
    __syncthreads();
    const int cn = (NN + HBLK-1)/HBLK;
    const int nEnd = min((b+1)*cn, NN);
    for (int i = b*cn + tid; i < nEnd; i += 256) atomicAdd(&h[ntype[i]], 1);
    __syncthreads();
    if (tid < NT) nhist[b*NT + tid] = h[tid];
}
__global__ void k_nscan(const int* __restrict__ nhist, int* __restrict__ noff, int* __restrict__ nbase,
                        int* __restrict__ tlist, int* __restrict__ tcount)
{
    __shared__ int tot[NT];
    const int tid = threadIdx.x;
    if (tid < NT){
        int s = 0;
        for (int b = 0; b < HBLK; b++) s += nhist[b*NT + tid];
        tot[tid] = s;
    }
    __syncthreads();
    if (tid == 0){ noff[0]=0; for (int t=0;t<NT;t++) noff[t+1]=noff[t]+tot[t]; }
    if (tid < NT){
        int base = 0; for (int t=0;t<tid;t++) base += tot[t];
        int run = 0;
        for (int b=0;b<HBLK;b++){ nbase[b*NT+tid] = base + run; run += nhist[b*NT+tid]; }
    }
    __syncthreads();
    if (tid == 0){
        int c = 0;
        for (int t = 0; t < NT; t++){
            const int ntile = (tot[t] + 15) >> 4;
            for (int rt = 0; rt < ntile; rt++) tlist[c++] = (t << 20) | rt;
        }
        *tcount = c;
    }
}
__global__ __launch_bounds__(256) void k_nscatter(const int* __restrict__ ntype,
    const int* __restrict__ nbase, int* __restrict__ nbucket)
{
    __shared__ int cur[NT];
    const int tid = threadIdx.x, b = blockIdx.x;
    if (tid < NT) cur[tid] = nbase[b*NT + tid];
    __syncthreads();
    const int cn = (NN + HBLK-1)/HBLK;
    const int nEnd = min((b+1)*cn, NN);
    for (int i = b*cn + tid; i < nEnd; i += 256)
        nbucket[atomicAdd(&cur[ntype[i]], 1)] = i;
}

// ---------- edge CSR build: sort by tgt ----------
__global__ void k_zero_bins(int* __restrict__ cnt){
    int i = blockIdx.x*256 + threadIdx.x;
    if (i < NN) cnt[i] = 0;
}
__global__ void k_csr_hist(const int* __restrict__ ei, int* __restrict__ cnt){
    int e = blockIdx.x*256 + threadIdx.x;
    if (e >= NE) return;
    atomicAdd(&cnt[ei[NE+e]], 1);
}
__global__ __launch_bounds__(256) void k_scan1(const int* __restrict__ cnt,
    int* __restrict__ tgt_off, int* __restrict__ bsum)
{
    __shared__ int sh[256];
    const int t = threadIdx.x, b = blockIdx.x;
    const int i = b*256 + t;
    const int v = (i < NN) ? cnt[i] : 0;
    sh[t] = v;
    __syncthreads();
    #pragma unroll
    for (int d = 1; d < 256; d <<= 1){
        const int u = (t >= d) ? sh[t-d] : 0;
        __syncthreads();
        sh[t] += u;
        __syncthreads();
    }
    if (i < NN) tgt_off[i] = sh[t] - v;
    if (t == 255) bsum[b] = sh[255];
}
__global__ __launch_bounds__(128) void k_scan2(const int* __restrict__ bsum,
    int* __restrict__ bbase, int* __restrict__ tgt_off)
{
    __shared__ int sh[128];
    const int t = threadIdx.x;
    const int v = (t < SCB) ? bsum[t] : 0;
    sh[t] = v;
    __syncthreads();
    #pragma unroll
    for (int d = 1; d < 128; d <<= 1){
        const int u = (t >= d) ? sh[t-d] : 0;
        __syncthreads();
        sh[t] += u;
        __syncthreads();
    }
    if (t < SCB) bbase[t] = sh[t] - v;
    if (t == 0) tgt_off[NN] = NE;
}
__global__ __launch_bounds__(256) void k_scan3(int* __restrict__ tgt_off,
    const int* __restrict__ bbase, int* __restrict__ binCur)
{
    const int i = blockIdx.x*256 + threadIdx.x;
    if (i >= NN) return;
    const int o = tgt_off[i] + bbase[blockIdx.x];
    tgt_off[i] = o;
    binCur[i] = o;
}
__global__ void k_csr_scatter(const int* __restrict__ ei, const int* __restrict__ etype,
    const int* __restrict__ etime, const int* __restrict__ ntype,
    int* __restrict__ binCur, int* __restrict__ src_s, int* __restrict__ combo_s,
    int* __restrict__ eid_s, int* __restrict__ tgt_s)
{
    int e = blockIdx.x*256 + threadIdx.x;
    if (e >= NE) return;
    const int tgt = ei[NE+e], r = etype[e], src = ei[e];
    const int pos = atomicAdd(&binCur[tgt], 1);
    src_s[pos] = src;
    combo_s[pos] = (etime[e]*NT + ntype[src]) | (r << 12);
    eid_s[pos] = e;
    tgt_s[pos] = tgt;
}

// ---------- weight pre-pack (merged): 36 big 256x256 mats -> frag-major f16 ----------
__global__ __launch_bounds__(256) void k_w2f16_big(
    const float* __restrict__ adaptW, const float* __restrict__ qW, const float* __restrict__ kW,
    const float* __restrict__ vW, const float* __restrict__ aW, _Float16* __restrict__ out)
{
    const int y = blockIdx.y;
    const float* src; int m;
    if (y < 4){ src = adaptW; m = y; }
    else if (y < 12){ src = qW; m = y-4; }
    else if (y < 20){ src = kW; m = y-12; }
    else if (y < 28){ src = vW; m = y-20; }
    else { src = aW; m = y-28; }
    const float* ip = src + (size_t)m*65536;
    _Float16* op = out + (size_t)y*65536;
    const int tid4 = blockIdx.x*256 + threadIdx.x;
    const int k4 = tid4 >> 8, c = tid4 & 255;
    f16x4 hv;
    #pragma unroll
    for (int j = 0; j < 4; j++)
        hv[j] = (_Float16)ip[(size_t)(((k4*4 + j) << 8) + c)];
    *reinterpret_cast<f16x4*>(&op[(size_t)tid4 * 4]) = hv;
}
// 256 rel 32x32 mats (att then msg) -> frag-major f16
__global__ __launch_bounds__(256) void k_w2f16_rel(
    const float* __restrict__ attW, const float* __restrict__ msgW, _Float16* __restrict__ out)
{
    const int y = blockIdx.y;
    const float* ip = (y < 128) ? (attW + (size_t)y*1024) : (msgW + (size_t)(y-128)*1024);
    _Float16* op = out + (size_t)y*1024;
    const int tid4 = threadIdx.x;
    const int k4 = tid4 >> 5, c = tid4 & 31;
    f16x4 hv;
    #pragma unroll
    for (int j = 0; j < 4; j++)
        hv[j] = (_Float16)ip[(size_t)(((k4*4 + j) << 5) + c)];
    *reinterpret_cast<f16x4*>(&op[(size_t)tid4 * 4]) = hv;
}

// ---------- typed MFMA GEMM: 16-row tiles, compact list; per-output dtype bitmask ----------
__global__ __launch_bounds__(256) void k_typed_mfma(
    const float* __restrict__ inF, const _Float16* __restrict__ inH,
    const _Float16* __restrict__ W0, const _Float16* __restrict__ W1, const _Float16* __restrict__ W2,
    const float* __restrict__ b0, const float* __restrict__ b1, const float* __restrict__ b2,
    void* __restrict__ o0, void* __restrict__ o1, void* __restrict__ o2,
    const int* __restrict__ nbucket, const int* __restrict__ noff,
    const int* __restrict__ tlist, const int* __restrict__ tcount,
    int nsel, int mode, int out_half_mask, const float* __restrict__ skipv, const float* __restrict__ xold)
{
    if ((int)blockIdx.x >= *tcount) return;
    const int ent = tlist[blockIdx.x];
    const int t = ent >> 20, rowTile = ent & 0xFFFFF;
    const int start = noff[t], cnt = noff[t+1] - start;

    const int tid = threadIdx.x;
    const int w = tid >> 6, lane = tid & 63;
    const int lrow = lane & 15, lgrp = lane >> 4;

    __shared__ _Float16 Al[16][260];
    __shared__ int nid[16];

    if (tid < 16){
        const int gr = rowTile*16 + tid;
        nid[tid] = (gr < cnt) ? nbucket[start + gr] : -1;
    }
    __syncthreads();

    // stage A once: 16 threads per row
    {
        const int r = tid >> 4;
        const int arow = nid[r];
        if (inH){
            const _Float16* ap = (arow >= 0) ? (inH + (size_t)arow*HD) : nullptr;
            #pragma unroll
            for (int j = 0; j < 4; j++){
                const int f4 = (tid & 15) + j*16;
                f16x4 hv = {0,0,0,0};
                if (ap) hv = *reinterpret_cast<const f16x4*>(ap + f4*4);
                *reinterpret_cast<f16x4*>(&Al[r][f4*4]) = hv;
            }
        } else {
            const float* ap = (arow >= 0) ? (inF + (size_t)arow*HD) : nullptr;
            #pragma unroll
            for (int j = 0; j < 4; j++){
                const int f4 = (tid & 15) + j*16;
                float4 v = make_float4(0.f,0.f,0.f,0.f);
                if (ap) v = *reinterpret_cast<const float4*>(ap + f4*4);
                f16x4 hv;
                hv[0]=(_Float16)v.x; hv[1]=(_Float16)v.y; hv[2]=(_Float16)v.z; hv[3]=(_Float16)v.w;
                *reinterpret_cast<f16x4*>(&Al[r][f4*4]) = hv;
            }
        }
    }
    __syncthreads();

    float sk = 0.f;
    if (mode == 2) sk = 1.f/(1.f + __expf(-skipv[t]));

    auto proc = [&](const _Float16* Wb, const float* bb, void* out, int oh){
        const _Float16* W = Wb + (size_t)t*HD*HD;
        const float* bias = bb + (size_t)t*HD;
        f32x4v acc[4];
        #pragma unroll
        for (int cs = 0; cs < 4; cs++) acc[cs] = (f32x4v){0.f,0.f,0.f,0.f};
        #pragma unroll 4
        for (int kc = 0; kc < 16; kc++){
            f16x4 bf[4];
            #pragma unroll
            for (int cs = 0; cs < 4; cs++)
                bf[cs] = *reinterpret_cast<const f16x4*>(
                    &W[(size_t)((kc*4 + lgrp)*HD + w*64 + cs*16 + lrow)*4]);
            const f16x4 af = *reinterpret_cast<const f16x4*>(&Al[lrow][kc*16 + lgrp*4]);
            #pragma unroll
            for (int cs = 0; cs < 4; cs++)
                acc[cs] = __builtin_amdgcn_mfma_f32_16x16x16f16(af, bf[cs], acc[cs], 0,0,0);
        }
        #pragma unroll
        for (int cs = 0; cs < 4; cs++){
            const int col = w*64 + cs*16 + lrow;
            const float bcol = bias[col];
            #pragma unroll
            for (int i = 0; i < 4; i++){
                const int lr = lgrp*4 + i;
                const int gr = rowTile*16 + lr;
                if (gr >= cnt) continue;
                const int node = nid[lr];
                float v = acc[cs][i] + bcol;
                if (mode == 1) v = tanhf(v);
                else if (mode == 2){
                    const float xo = xold[(size_t)node*HD + col];
                    v = v*sk + xo*(1.f - sk);
                }
                if (oh) ((_Float16*)out)[(size_t)node*HD + col] = (_Float16)v;
                else    ((float*)out)[(size_t)node*HD + col] = v;
            }
        }
    };

    proc(W0, b0, o0, out_half_mask & 1);
    if (nsel > 1){
        proc(W1, b1, o1, (out_half_mask >> 1) & 1);
        proc(W2, b2, o2, (out_half_mask >> 2) & 1);
    }
}

// ---------- small row GEMM: C[row, ty] = A[row] @ W[ty] (+bias), f32 or f16 out ----------
__global__ __launch_bounds__(256) void k_row_gemm(
    const float* __restrict__ A, const float* __restrict__ Wb, const float* __restrict__ bias,
    void* __restrict__ C, int c_stride, int out_half)
{
    const int row = blockIdx.x, ty = blockIdx.y, d = threadIdx.x;
    const float* W = Wb + (size_t)ty*HD*HD;
    __shared__ float ar[HD];
    ar[d] = A[(size_t)row*HD + d];
    __syncthreads();
    float acc = bias ? bias[d] : 0.f;
    #pragma unroll 8
    for (int k=0;k<HD;k++) acc = fmaf(ar[k], W[(size_t)k*HD + d], acc);
    if (out_half) ((_Float16*)C)[(size_t)row*c_stride + ty*HD + d] = (_Float16)acc;
    else          ((float*)C)[(size_t)row*c_stride + ty*HD + d] = acc;
}

// ---------- MFMA fold, node+combo merged: blocks [0,FOLDN) node, [FOLDN,FOLDN+FOLDC) combo ----------
__global__ __launch_bounds__(256) void k_fold_mfma(
    const _Float16* __restrict__ INn, const _Float16* __restrict__ INc,
    const _Float16* __restrict__ MATF,
    _Float16* __restrict__ OUTn, _Float16* __restrict__ OUTc)
{
    const int r = blockIdx.y;
    const bool isC = (int)blockIdx.x >= FOLDN;
    const int bx0 = isC ? (int)blockIdx.x - FOLDN : (int)blockIdx.x;
    const _Float16* IN = isC ? INc : INn;
    _Float16* OUT = isC ? OUTc : OUTn;
    const int M = isC ? (MAXL*NT) : NN;
    const int bstride = (isC ? FOLDC : FOLDN) * 4;

    const int lane = threadIdx.x & 63, w = threadIdx.x >> 6;
    const int lrow = lane & 15, lgrp = lane >> 4;
    f16x4 b[NH][2][2];
    const _Float16* Mr = MATF + (size_t)r*NH*1024;
    #pragma unroll
    for (int h = 0; h < NH; h++)
      #pragma unroll
      for (int kb = 0; kb < 2; kb++)
        #pragma unroll
        for (int hf = 0; hf < 2; hf++)
            b[h][kb][hf] = *reinterpret_cast<const f16x4*>(
                &Mr[(size_t)h*1024 + (size_t)(((kb*4 + lgrp)*32) + hf*16 + lrow)*4]);
    const int ntiles = M >> 4;
    for (int t = bx0*4 + w; t < ntiles; t += bstride){
        const int row0 = t*16;
        const _Float16* inrow = IN + (size_t)(row0 + lrow)*HD;
        f16x4 a[NH][2];
        #pragma unroll
        for (int h = 0; h < NH; h++)
          #pragma unroll
          for (int kb = 0; kb < 2; kb++)
              a[h][kb] = *reinterpret_cast<const f16x4*>(&inrow[h*32 + kb*16 + lgrp*4]);
        #pragma unroll
        for (int h = 0; h < NH; h++){
          #pragma unroll
          for (int hf = 0; hf < 2; hf++){
              f32x4v acc = {0.f,0.f,0.f,0.f};
              acc = __builtin_amdgcn_mfma_f32_16x16x16f16(a[h][0], b[h][0][hf], acc, 0,0,0);
              acc = __builtin_amdgcn_mfma_f32_16x16x16f16(a[h][1], b[h][1][hf], acc, 0,0,0);
              #pragma unroll
              for (int i = 0; i < 4; i++){
                  const int rr = lgrp*4 + i;
                  OUT[((size_t)(row0+rr)*NR + r)*HD + h*32 + hf*16 + lrow] = (_Float16)acc[i];
              }
          }
        }
    }
}

// ---------- edge scores (streaming, wave per edge; f32 q for softmax precision) ----------
__global__ __launch_bounds__(256) void k_score(
    const float* __restrict__ q0, const _Float16* __restrict__ kA, const _Float16* __restrict__ KcA,
    const float* __restrict__ relP,
    const int* __restrict__ src_s, const int* __restrict__ combo_s, const int* __restrict__ tgt_s,
    float* __restrict__ s_arr)
{
    const int j = blockIdx.x*4 + (threadIdx.x >> 6);
    if (j >= NE) return;
    const int lane = threadIdx.x & 63;
    const int h = lane >> 3, c4 = (lane & 7) << 2;
    const int src = src_s[j];
    const int cw  = combo_s[j];
    const int tgt = tgt_s[j];
    const int r = cw >> 12, combo = cw & 0xFFF;

    const float4 q4 = *reinterpret_cast<const float4*>(&q0[(size_t)tgt*HD + h*32 + c4]);
    const f16x4 ka = *reinterpret_cast<const f16x4*>(&kA[((size_t)src*NR + r)*HD + h*32 + c4]);
    const f16x4 kc = *reinterpret_cast<const f16x4*>(&KcA[((size_t)combo*NR + r)*HD + h*32 + c4]);
    float v = q4.x*((float)ka[0]+(float)kc[0])
            + q4.y*((float)ka[1]+(float)kc[1])
            + q4.z*((float)ka[2]+(float)kc[2])
            + q4.w*((float)ka[3]+(float)kc[3]);
    v += __shfl_xor(v, 1); v += __shfl_xor(v, 2); v += __shfl_xor(v, 4);
    if ((lane & 7) == 0)
        s_arr[(size_t)j*NH + h] = v * relP[r*NH + h] * INV_SQRT_DK;
}

// ---------- node-parallel segment softmax (CSR) ----------
__global__ __launch_bounds__(256) void k_softmax(
    float* __restrict__ s_arr, const int* __restrict__ tgt_off, const int* __restrict__ eid_s,
    float* __restrict__ out_att, int store)
{
    const int idx = blockIdx.x*256 + threadIdx.x;
    if (idx >= NN*NH) return;
    const int n = idx >> 3, h = idx & 7;
    const int e0 = tgt_off[n], e1 = tgt_off[n+1];
    if (e0 == e1) return;
    float m = -INFINITY;
    for (int j = e0; j < e1; j++) m = fmaxf(m, s_arr[(size_t)j*NH + h]);
    float l = 0.f;
    for (int j = e0; j < e1; j++) l += __expf(s_arr[(size_t)j*NH + h] - m);
    const float inv = 1.f / l;
    for (int j = e0; j < e1; j++){
        const float a = __expf(s_arr[(size_t)j*NH + h] - m) * inv;
        s_arr[(size_t)j*NH + h] = a;
        if (store) out_att[(size_t)eid_s[j]*NH + h] = a;
    }
}

// ---------- aggregation (CSR, wave per node), gelu fused, f16 out ----------
__global__ __launch_bounds__(256) void k_agg(
    const _Float16* __restrict__ vM, const _Float16* __restrict__ VcM,
    const float* __restrict__ alpha,
    const int* __restrict__ tgt_off, const int* __restrict__ src_s, const int* __restrict__ combo_s,
    _Float16* __restrict__ agg)
{
    const int n = blockIdx.x*4 + (threadIdx.x >> 6);
    if (n >= NN) return;
    const int lane = threadIdx.x & 63;
    const int h = lane >> 3, c4 = (lane & 7) << 2;
    const int col = h*32 + c4;
    const int e0 = tgt_off[n], e1 = tgt_off[n+1];
    float a0=0.f, a1=0.f, a2=0.f, a3=0.f;
    for (int j = e0; j < e1; j++){
        const int src = src_s[j];
        const int cw  = combo_s[j];
        const int r = cw >> 12, combo = cw & 0xFFF;
        const float al = alpha[(size_t)j*NH + h];
        const f16x4 vm = *reinterpret_cast<const f16x4*>(&vM[((size_t)src*NR + r)*HD + col]);
        const f16x4 vc = *reinterpret_cast<const f16x4*>(&VcM[((size_t)combo*NR + r)*HD + col]);
        a0 = fmaf(al, (float)vm[0] + (float)vc[0], a0);
        a1 = fmaf(al, (float)vm[1] + (float)vc[1], a1);
        a2 = fmaf(al, (float)vm[2] + (float)vc[2], a2);
        a3 = fmaf(al, (float)vm[3] + (float)vc[3], a3);
    }
    f16x4 o;
    o[0] = (_Float16)(0.5f*a0*(1.f + erff(a0*0.70710678118654752f)));
    o[1] = (_Float16)(0.5f*a1*(1.f + erff(a1*0.70710678118654752f)));
    o[2] = (_Float16)(0.5f*a2*(1.f + erff(a2*0.70710678118654752f)));
    o[3] = (_Float16)(0.5f*a3*(1.f + erff(a3*0.70710678118654752f)));
    *reinterpret_cast<f16x4*>(&agg[(size_t)n*HD + col]) = o;
}

__global__ void k_copy(const float* __restrict__ s, float* __restrict__ d, int n){
    int i = blockIdx.x*256 + threadIdx.x;
    if (i < n) d[i] = s[i];
}

extern "C" void kernel_launch(void* const* d_in, const int* in_sizes, int n_in,
                              void* d_out, int out_size, void* d_ws, size_t ws_size,
                              hipStream_t stream)
{
    const float* node_feature = (const float*)d_in[0];
    const int*   node_type    = (const int*)d_in[1];
    const int*   edge_time    = (const int*)d_in[2];
    const int*   edge_index   = (const int*)d_in[3];
    const int*   edge_type    = (const int*)d_in[4];
    const float* adapt_W = (const float*)d_in[5];
    const float* adapt_b = (const float*)d_in[6];
    const float* k_W = (const float*)d_in[7];
    const float* k_b = (const float*)d_in[8];
    const float* q_W = (const float*)d_in[9];
    const float* q_b = (const float*)d_in[10];
    const float* v_W = (const float*)d_in[11];
    const float* v_b = (const float*)d_in[12];
    const float* a_W = (const float*)d_in[13];
    const float* a_b = (const float*)d_in[14];
    const float* rel_pri = (const float*)d_in[15];
    const float* rel_att = (const float*)d_in[16];
    const float* rel_msg = (const float*)d_in[17];
    const float* skip  = (const float*)d_in[18];
    const float* rte_W = (const float*)d_in[19];
    const float* rte_b = (const float*)d_in[20];
    const float* rte_emb = (const float*)d_in[21];

    char* wp = (char*)d_ws;
    auto alloc_f = [&](size_t n)->float*{ float* p=(float*)wp; wp += n*sizeof(float); return p; };
    auto alloc_i = [&](size_t n)->int*  { int*   p=(int*)wp;   wp += n*sizeof(int);   return p; };
    auto alloc_h = [&](size_t n)->_Float16*{ _Float16* p=(_Float16*)wp; wp += n*sizeof(_Float16); return p; };
    float* xA    = alloc_f((size_t)NN*HD);
    float* xB    = alloc_f((size_t)NN*HD);
    float* q0f   = alloc_f((size_t)NN*HD);
    _Float16* k0h = alloc_h((size_t)NN*HD);
    _Float16* v0h = alloc_h((size_t)NN*HD);
    _Float16* aggh= alloc_h((size_t)NN*HD);
    float* s_arr = alloc_f((size_t)NE*NH);
    float* rteP  = alloc_f((size_t)MAXL*HD);
    _Float16* Kch = alloc_h((size_t)MAXL*NT*HD);
    _Float16* Vch = alloc_h((size_t)MAXL*NT*HD);
    _Float16* kavm = alloc_h((size_t)NN*NR*HD);        // kA then reused for vM
    _Float16* kca  = alloc_h((size_t)MAXL*NT*NR*HD);   // KcA then reused for VcM
    _Float16* wF   = alloc_h((size_t)36*65536);        // adapt|q|k|v|a frag-major
    _Float16* relF = alloc_h((size_t)256*1024);        // att(128) | msg(128)
    int* nbucket = alloc_i(NN);
    int* nhist   = alloc_i(HBLK*NT);
    int* nbase   = alloc_i(HBLK*NT);
    int* noff    = alloc_i(8);
    int* tlist   = alloc_i(TMAX);
    int* tcount  = alloc_i(8);
    int* cnt     = alloc_i(NN);
    int* bsum    = alloc_i(SCB);
    int* bbase   = alloc_i(SCB);
    int* binCur  = alloc_i(NN);
    int* tgt_off = alloc_i(NN+1);
    int* src_s   = alloc_i(NE);
    int* combo_s = alloc_i(NE);
    int* eid_s   = alloc_i(NE);
    int* tgt_s   = alloc_i(NE);

    const _Float16* adaptF = wF;
    const _Float16* qF = wF + (size_t)4*65536;
    const _Float16* kF = wF + (size_t)12*65536;
    const _Float16* vF = wF + (size_t)20*65536;
    const _Float16* aF = wF + (size_t)28*65536;
    const _Float16* relAF = relF;
    const _Float16* relMF = relF + (size_t)128*1024;

    float* out_att = (float*)d_out;
    float* out_x   = (float*)d_out + (size_t)NE*NH;

    const dim3 gFold(FOLDN + FOLDC, NR);
    const int gE256 = (NE + 255)/256;
    const int gNH = (NN*HD + 255)/256;
    const int gSc = (NE + 3)/4;
    const int gSm = (NN*NH + 255)/256;
    const int gAg = (NN + 3)/4;

    // weight pre-pack to f16 fragment-major (2 merged launches)
    k_w2f16_big<<<dim3(64,36),256,0,stream>>>(adapt_W, q_W, k_W, v_W, a_W, wF);
    k_w2f16_rel<<<dim3(1,256),256,0,stream>>>(rel_att, rel_msg, relF);

    // node buckets (by type) + compact 16-row tile list
    k_nhist<<<HBLK,256,0,stream>>>(node_type, nhist);
    k_nscan<<<1,64,0,stream>>>(nhist, noff, nbase, tlist, tcount);
    k_nscatter<<<HBLK,256,0,stream>>>(node_type, nbase, nbucket);

    // edge CSR sorted by tgt
    k_zero_bins<<<SCB,256,0,stream>>>(cnt);
    k_csr_hist<<<gE256,256,0,stream>>>(edge_index, cnt);
    k_scan1<<<SCB,256,0,stream>>>(cnt, tgt_off, bsum);
    k_scan2<<<1,128,0,stream>>>(bsum, bbase, tgt_off);
    k_scan3<<<SCB,256,0,stream>>>(tgt_off, bbase, binCur);
    k_csr_scatter<<<gE256,256,0,stream>>>(edge_index, edge_type, edge_time, node_type,
                                          binCur, src_s, combo_s, eid_s, tgt_s);

    // adapt: x = tanh(node_feature @ adapt_W[t] + b)   (f32 in, f32 out)
    k_typed_mfma<<<TMAX,256,0,stream>>>(node_feature, nullptr, adaptF, nullptr, nullptr,
                                        adapt_b, nullptr, nullptr,
                                        xA, nullptr, nullptr,
                                        nbucket, noff, tlist, tcount, 1, 1, 0, nullptr, nullptr);

    const float* x_in = xA;
    float* x_out = xB;
    for (int l = 0; l < NL; l++){
        k_row_gemm<<<dim3(MAXL,1),256,0,stream>>>(rte_emb, rte_W + (size_t)l*HD*HD,
                                                  rte_b + (size_t)l*HD, rteP, HD, 0);
        k_row_gemm<<<dim3(MAXL,NT),256,0,stream>>>(rteP, k_W + (size_t)l*NT*HD*HD, nullptr, Kch, NT*HD, 1);
        k_row_gemm<<<dim3(MAXL,NT),256,0,stream>>>(rteP, v_W + (size_t)l*NT*HD*HD, nullptr, Vch, NT*HD, 1);
        // fused Q/K/V node-level GEMM: q -> f32 (softmax precision), k/v -> f16
        k_typed_mfma<<<TMAX,256,0,stream>>>(x_in, nullptr,
                                            qF + (size_t)l*NT*HD*HD, kF + (size_t)l*NT*HD*HD, vF + (size_t)l*NT*HD*HD,
                                            q_b + (size_t)l*NT*HD,  k_b + (size_t)l*NT*HD,  v_b + (size_t)l*NT*HD,
                                            q0f, k0h, v0h,
                                            nbucket, noff, tlist, tcount, 3, 0, 6, nullptr, nullptr);
        // fold rel_att into node-level + combo-level tables (merged)
        k_fold_mfma<<<gFold,256,0,stream>>>(k0h, Kch, relAF + (size_t)l*NR*NH*1024, kavm, kca);
        // scores + softmax
        k_score<<<gSc,256,0,stream>>>(q0f, kavm, kca, rel_pri + (size_t)l*NR*NH,
                                      src_s, combo_s, tgt_s, s_arr);
        const int store_s = (l == NL-1) ? 1 : 0;
        k_softmax<<<gSm,256,0,stream>>>(s_arr, tgt_off, eid_s, out_att, store_s);
        // fold rel_msg (merged), then aggregate (+gelu, f16 out)
        k_fold_mfma<<<gFold,256,0,stream>>>(v0h, Vch, relMF + (size_t)l*NR*NH*1024, kavm, kca);
        k_agg<<<gAg,256,0,stream>>>(kavm, kca, s_arr, tgt_off, src_s, combo_s, aggh);
        // output transform + skip (f16 in, f32 out)
        k_typed_mfma<<<TMAX,256,0,stream>>>(nullptr, aggh,
                                            aF + (size_t)l*NT*HD*HD, nullptr, nullptr,
                                            a_b + (size_t)l*NT*HD, nullptr, nullptr,
                                            x_out, nullptr, nullptr,
                                            nbucket, noff, tlist, tcount, 1, 2, 0, skip + (size_t)l*NT, x_in);
        float* tmp = (float*)x_in; x_in = x_out; x_out = tmp;
    }
    k_copy<<<gNH,256,0,stream>>>(x_in, out_x, NN*HD);
}

// Round 18
// 602.044 us; speedup vs baseline: 1.1255x; 1.1255x over previous
//
#include <hip/hip_runtime.h>
#include <hip/hip_fp16.h>

#define NN    20000
#define NE    150000
#define HD    256
#define NT    4
#define NR    8
#define NH    8
#define DKq   32
#define NL    2
#define MAXL  240
#define HBLK  256
#define SCB   ((NN + 255)/256)
#define TMAX  632
#define FOLDN 79
#define FOLDC 15
#define INV_SQRT_DK 0.17677669529663687f

typedef _Float16 f16x4 __attribute__((ext_vector_type(4)));
typedef float    f32x4v __attribute__((ext_vector_type(4)));

// ---------- node bucketing (by type) + compact 32-row tile list ----------
__global__ __launch_bounds__(256) void k_nhist(const int* __restrict__ ntype, int* __restrict__ nhist)
{
    __shared__ int h[NT];
    const int tid = threadIdx.x, b = blockIdx.x;
    if (tid < NT) h[tid] = 0;
    __syncthreads();
    const int cn = (NN + HBLK-1)/HBLK;
    const int nEnd = min((b+1)*cn, NN);
    for (int i = b*cn + tid; i < nEnd; i += 256) atomicAdd(&h[ntype[i]], 1);
    __syncthreads();
    if (tid < NT) nhist[b*NT + tid] = h[tid];
}
__global__ void k_nscan(const int* __restrict__ nhist, int* __restrict__ noff, int* __restrict__ nbase,
                        int* __restrict__ tlist, int* __restrict__ tcount)
{
    __shared__ int tot[NT];
    const int tid = threadIdx.x;
    if (tid < NT){
        int s = 0;
        for (int b = 0; b < HBLK; b++) s += nhist[b*NT + tid];
        tot[tid] = s;
    }
    __syncthreads();
    if (tid == 0){ noff[0]=0; for (int t=0;t<NT;t++) noff[t+1]=noff[t]+tot[t]; }
    if (tid < NT){
        int base = 0; for (int t=0;t<tid;t++) base += tot[t];
        int run = 0;
        for (int b=0;b<HBLK;b++){ nbase[b*NT+tid] = base + run; run += nhist[b*NT+tid]; }
    }
    __syncthreads();
    if (tid == 0){
        int c = 0;
        for (int t = 0; t < NT; t++){
            const int ntile = (tot[t] + 31) >> 5;
            for (int rt = 0; rt < ntile; rt++) tlist[c++] = (t << 20) | rt;
        }
        *tcount = c;
    }
}
__global__ __launch_bounds__(256) void k_nscatter(const int* __restrict__ ntype,
    const int* __restrict__ nbase, int* __restrict__ nbucket)
{
    __shared__ int cur[NT];
    const int tid = threadIdx.x, b = blockIdx.x;
    if (tid < NT) cur[tid] = nbase[b*NT + tid];
    __syncthreads();
    const int cn = (NN + HBLK-1)/HBLK;
    const int nEnd = min((b+1)*cn, NN);
    for (int i = b*cn + tid; i < nEnd; i += 256)
        nbucket[atomicAdd(&cur[ntype[i]], 1)] = i;
}

// ---------- edge CSR build: sort by tgt ----------
__global__ void k_zero_bins(int* __restrict__ cnt){
    int i = blockIdx.x*256 + threadIdx.x;
    if (i < NN) cnt[i] = 0;
}
__global__ void k_csr_hist(const int* __restrict__ ei, int* __restrict__ cnt){
    int e = blockIdx.x*256 + threadIdx.x;
    if (e >= NE) return;
    atomicAdd(&cnt[ei[NE+e]], 1);
}
__global__ __launch_bounds__(256) void k_scan1(const int* __restrict__ cnt,
    int* __restrict__ tgt_off, int* __restrict__ bsum)
{
    __shared__ int sh[256];
    const int t = threadIdx.x, b = blockIdx.x;
    const int i = b*256 + t;
    const int v = (i < NN) ? cnt[i] : 0;
    sh[t] = v;
    __syncthreads();
    #pragma unroll
    for (int d = 1; d < 256; d <<= 1){
        const int u = (t >= d) ? sh[t-d] : 0;
        __syncthreads();
        sh[t] += u;
        __syncthreads();
    }
    if (i < NN) tgt_off[i] = sh[t] - v;
    if (t == 255) bsum[b] = sh[255];
}
__global__ __launch_bounds__(128) void k_scan2(const int* __restrict__ bsum,
    int* __restrict__ bbase, int* __restrict__ tgt_off)
{
    __shared__ int sh[128];
    const int t = threadIdx.x;
    const int v = (t < SCB) ? bsum[t] : 0;
    sh[t] = v;
    __syncthreads();
    #pragma unroll
    for (int d = 1; d < 128; d <<= 1){
        const int u = (t >= d) ? sh[t-d] : 0;
        __syncthreads();
        sh[t] += u;
        __syncthreads();
    }
    if (t < SCB) bbase[t] = sh[t] - v;
    if (t == 0) tgt_off[NN] = NE;
}
__global__ __launch_bounds__(256) void k_scan3(int* __restrict__ tgt_off,
    const int* __restrict__ bbase, int* __restrict__ binCur)
{
    const int i = blockIdx.x*256 + threadIdx.x;
    if (i >= NN) return;
    const int o = tgt_off[i] + bbase[blockIdx.x];
    tgt_off[i] = o;
    binCur[i] = o;
}
__global__ void k_csr_scatter(const int* __restrict__ ei, const int* __restrict__ etype,
    const int* __restrict__ etime, const int* __restrict__ ntype,
    int* __restrict__ binCur, int* __restrict__ src_s, int* __restrict__ combo_s,
    int* __restrict__ eid_s, int* __restrict__ tgt_s)
{
    int e = blockIdx.x*256 + threadIdx.x;
    if (e >= NE) return;
    const int tgt = ei[NE+e], r = etype[e], src = ei[e];
    const int pos = atomicAdd(&binCur[tgt], 1);
    src_s[pos] = src;
    combo_s[pos] = (etime[e]*NT + ntype[src]) | (r << 12);
    eid_s[pos] = e;
    tgt_s[pos] = tgt;
}

// ---------- weight pre-pack (merged): 36 big 256x256 mats -> frag-major f16 ----------
__global__ __launch_bounds__(256) void k_w2f16_big(
    const float* __restrict__ adaptW, const float* __restrict__ qW, const float* __restrict__ kW,
    const float* __restrict__ vW, const float* __restrict__ aW, _Float16* __restrict__ out)
{
    const int y = blockIdx.y;
    const float* src; int m;
    if (y < 4){ src = adaptW; m = y; }
    else if (y < 12){ src = qW; m = y-4; }
    else if (y < 20){ src = kW; m = y-12; }
    else if (y < 28){ src = vW; m = y-20; }
    else { src = aW; m = y-28; }
    const float* ip = src + (size_t)m*65536;
    _Float16* op = out + (size_t)y*65536;
    const int tid4 = blockIdx.x*256 + threadIdx.x;
    const int k4 = tid4 >> 8, c = tid4 & 255;
    f16x4 hv;
    #pragma unroll
    for (int j = 0; j < 4; j++)
        hv[j] = (_Float16)ip[(size_t)(((k4*4 + j) << 8) + c)];
    *reinterpret_cast<f16x4*>(&op[(size_t)tid4 * 4]) = hv;
}
// 256 rel 32x32 mats (att then msg) -> frag-major f16
__global__ __launch_bounds__(256) void k_w2f16_rel(
    const float* __restrict__ attW, const float* __restrict__ msgW, _Float16* __restrict__ out)
{
    const int y = blockIdx.y;
    const float* ip = (y < 128) ? (attW + (size_t)y*1024) : (msgW + (size_t)(y-128)*1024);
    _Float16* op = out + (size_t)y*1024;
    const int tid4 = threadIdx.x;
    const int k4 = tid4 >> 5, c = tid4 & 31;
    f16x4 hv;
    #pragma unroll
    for (int j = 0; j < 4; j++)
        hv[j] = (_Float16)ip[(size_t)(((k4*4 + j) << 5) + c)];
    *reinterpret_cast<f16x4*>(&op[(size_t)tid4 * 4]) = hv;
}

// ---------- typed MFMA GEMM: 32-row tiles, compact list; per-output dtype bitmask ----------
__global__ __launch_bounds__(256) void k_typed_mfma(
    const float* __restrict__ inF, const _Float16* __restrict__ inH,
    const _Float16* __restrict__ W0, const _Float16* __restrict__ W1, const _Float16* __restrict__ W2,
    const float* __restrict__ b0, const float* __restrict__ b1, const float* __restrict__ b2,
    void* __restrict__ o0, void* __restrict__ o1, void* __restrict__ o2,
    const int* __restrict__ nbucket, const int* __restrict__ noff,
    const int* __restrict__ tlist, const int* __restrict__ tcount,
    int nsel, int mode, int out_half_mask, const float* __restrict__ skipv, const float* __restrict__ xold)
{
    if ((int)blockIdx.x >= *tcount) return;
    const int ent = tlist[blockIdx.x];
    const int t = ent >> 20, rowTile = ent & 0xFFFFF;
    const int start = noff[t], cnt = noff[t+1] - start;

    const int tid = threadIdx.x;
    const int w = tid >> 6, lane = tid & 63;
    const int lrow = lane & 15, lgrp = lane >> 4;

    __shared__ _Float16 Al[32][260];
    __shared__ int nid[32];

    if (tid < 32){
        const int gr = rowTile*32 + tid;
        nid[tid] = (gr < cnt) ? nbucket[start + gr] : -1;
    }
    __syncthreads();

    // stage A once: 8 threads per row
    {
        const int r = tid >> 3;
        const int arow = nid[r];
        if (inH){
            const _Float16* ap = (arow >= 0) ? (inH + (size_t)arow*HD) : nullptr;
            #pragma unroll
            for (int j = 0; j < 8; j++){
                const int f4 = (tid & 7) + j*8;
                f16x4 hv = {0,0,0,0};
                if (ap) hv = *reinterpret_cast<const f16x4*>(ap + f4*4);
                *reinterpret_cast<f16x4*>(&Al[r][f4*4]) = hv;
            }
        } else {
            const float* ap = (arow >= 0) ? (inF + (size_t)arow*HD) : nullptr;
            #pragma unroll
            for (int j = 0; j < 8; j++){
                const int f4 = (tid & 7) + j*8;
                float4 v = make_float4(0.f,0.f,0.f,0.f);
                if (ap) v = *reinterpret_cast<const float4*>(ap + f4*4);
                f16x4 hv;
                hv[0]=(_Float16)v.x; hv[1]=(_Float16)v.y; hv[2]=(_Float16)v.z; hv[3]=(_Float16)v.w;
                *reinterpret_cast<f16x4*>(&Al[r][f4*4]) = hv;
            }
        }
    }
    __syncthreads();

    float sk = 0.f;
    if (mode == 2) sk = 1.f/(1.f + __expf(-skipv[t]));

    auto proc = [&](const _Float16* Wb, const float* bb, void* out, int oh){
        const _Float16* W = Wb + (size_t)t*HD*HD;
        const float* bias = bb + (size_t)t*HD;
        f32x4v acc[4][2];
        #pragma unroll
        for (int cs = 0; cs < 4; cs++){
            acc[cs][0] = (f32x4v){0.f,0.f,0.f,0.f};
            acc[cs][1] = (f32x4v){0.f,0.f,0.f,0.f};
        }
        #pragma unroll 4
        for (int kc = 0; kc < 16; kc++){
            f16x4 bf[4];
            #pragma unroll
            for (int cs = 0; cs < 4; cs++)
                bf[cs] = *reinterpret_cast<const f16x4*>(
                    &W[(size_t)((kc*4 + lgrp)*HD + w*64 + cs*16 + lrow)*4]);
            const f16x4 af0 = *reinterpret_cast<const f16x4*>(&Al[lrow][kc*16 + lgrp*4]);
            const f16x4 af1 = *reinterpret_cast<const f16x4*>(&Al[16 + lrow][kc*16 + lgrp*4]);
            #pragma unroll
            for (int cs = 0; cs < 4; cs++){
                acc[cs][0] = __builtin_amdgcn_mfma_f32_16x16x16f16(af0, bf[cs], acc[cs][0], 0,0,0);
                acc[cs][1] = __builtin_amdgcn_mfma_f32_16x16x16f16(af1, bf[cs], acc[cs][1], 0,0,0);
            }
        }
        #pragma unroll
        for (int cs = 0; cs < 4; cs++){
            const int col = w*64 + cs*16 + lrow;
            const float bcol = bias[col];
            #pragma unroll
            for (int rt = 0; rt < 2; rt++){
                #pragma unroll
                for (int i = 0; i < 4; i++){
                    const int lr = rt*16 + lgrp*4 + i;
                    const int gr = rowTile*32 + lr;
                    if (gr >= cnt) continue;
                    const int node = nid[lr];
                    float v = acc[cs][rt][i] + bcol;
                    if (mode == 1) v = tanhf(v);
                    else if (mode == 2){
                        const float xo = xold[(size_t)node*HD + col];
                        v = v*sk + xo*(1.f - sk);
                    }
                    if (oh) ((_Float16*)out)[(size_t)node*HD + col] = (_Float16)v;
                    else    ((float*)out)[(size_t)node*HD + col] = v;
                }
            }
        }
    };

    proc(W0, b0, o0, out_half_mask & 1);
    if (nsel > 1){
        proc(W1, b1, o1, (out_half_mask >> 1) & 1);
        proc(W2, b2, o2, (out_half_mask >> 2) & 1);
    }
}

// ---------- small row GEMM: rteP = rte_emb @ rte_W + rte_b (f32 out) ----------
__global__ __launch_bounds__(256) void k_row_gemm(
    const float* __restrict__ A, const float* __restrict__ W, const float* __restrict__ bias,
    float* __restrict__ C)
{
    const int row = blockIdx.x, d = threadIdx.x;
    __shared__ float ar[HD];
    ar[d] = A[(size_t)row*HD + d];
    __syncthreads();
    float acc = bias[d];
    #pragma unroll 8
    for (int k=0;k<HD;k++) acc = fmaf(ar[k], W[(size_t)k*HD + d], acc);
    C[(size_t)row*HD + d] = acc;
}
// merged Kc/Vc: z=0 -> k_W->Kch ; z=1 -> v_W->Vch   (f16 out)
__global__ __launch_bounds__(256) void k_row_gemm2(
    const float* __restrict__ A, const float* __restrict__ kWb, const float* __restrict__ vWb,
    _Float16* __restrict__ Kc, _Float16* __restrict__ Vc)
{
    const int row = blockIdx.x, ty = blockIdx.y, d = threadIdx.x;
    const float* W = ((blockIdx.z == 0) ? kWb : vWb) + (size_t)ty*HD*HD;
    _Float16* C = (blockIdx.z == 0) ? Kc : Vc;
    __shared__ float ar[HD];
    ar[d] = A[(size_t)row*HD + d];
    __syncthreads();
    float acc = 0.f;
    #pragma unroll 8
    for (int k=0;k<HD;k++) acc = fmaf(ar[k], W[(size_t)k*HD + d], acc);
    C[(size_t)row*(NT*HD) + ty*HD + d] = (_Float16)acc;
}

// ---------- MFMA fold, node+combo merged: blocks [0,FOLDN) node, [FOLDN,FOLDN+FOLDC) combo ----------
__global__ __launch_bounds__(256) void k_fold_mfma(
    const _Float16* __restrict__ INn, const _Float16* __restrict__ INc,
    const _Float16* __restrict__ MATF,
    _Float16* __restrict__ OUTn, _Float16* __restrict__ OUTc)
{
    const int r = blockIdx.y;
    const bool isC = (int)blockIdx.x >= FOLDN;
    const int bx0 = isC ? (int)blockIdx.x - FOLDN : (int)blockIdx.x;
    const _Float16* IN = isC ? INc : INn;
    _Float16* OUT = isC ? OUTc : OUTn;
    const int M = isC ? (MAXL*NT) : NN;
    const int bstride = (isC ? FOLDC : FOLDN) * 4;

    const int lane = threadIdx.x & 63, w = threadIdx.x >> 6;
    const int lrow = lane & 15, lgrp = lane >> 4;
    f16x4 b[NH][2][2];
    const _Float16* Mr = MATF + (size_t)r*NH*1024;
    #pragma unroll
    for (int h = 0; h < NH; h++)
      #pragma unroll
      for (int kb = 0; kb < 2; kb++)
        #pragma unroll
        for (int hf = 0; hf < 2; hf++)
            b[h][kb][hf] = *reinterpret_cast<const f16x4*>(
                &Mr[(size_t)h*1024 + (size_t)(((kb*4 + lgrp)*32) + hf*16 + lrow)*4]);
    const int ntiles = M >> 4;
    for (int t = bx0*4 + w; t < ntiles; t += bstride){
        const int row0 = t*16;
        const _Float16* inrow = IN + (size_t)(row0 + lrow)*HD;
        f16x4 a[NH][2];
        #pragma unroll
        for (int h = 0; h < NH; h++)
          #pragma unroll
          for (int kb = 0; kb < 2; kb++)
              a[h][kb] = *reinterpret_cast<const f16x4*>(&inrow[h*32 + kb*16 + lgrp*4]);
        #pragma unroll
        for (int h = 0; h < NH; h++){
          #pragma unroll
          for (int hf = 0; hf < 2; hf++){
              f32x4v acc = {0.f,0.f,0.f,0.f};
              acc = __builtin_amdgcn_mfma_f32_16x16x16f16(a[h][0], b[h][0][hf], acc, 0,0,0);
              acc = __builtin_amdgcn_mfma_f32_16x16x16f16(a[h][1], b[h][1][hf], acc, 0,0,0);
              #pragma unroll
              for (int i = 0; i < 4; i++){
                  const int rr = lgrp*4 + i;
                  OUT[((size_t)(row0+rr)*NR + r)*HD + h*32 + hf*16 + lrow] = (_Float16)acc[i];
              }
          }
        }
    }
}

// ---------- edge scores (streaming, wave per edge; f32 q for softmax precision) ----------
__global__ __launch_bounds__(256) void k_score(
    const float* __restrict__ q0, const _Float16* __restrict__ kA, const _Float16* __restrict__ KcA,
    const float* __restrict__ relP,
    const int* __restrict__ src_s, const int* __restrict__ combo_s, const int* __restrict__ tgt_s,
    float* __restrict__ s_arr)
{
    const int j = blockIdx.x*4 + (threadIdx.x >> 6);
    if (j >= NE) return;
    const int lane = threadIdx.x & 63;
    const int h = lane >> 3, c4 = (lane & 7) << 2;
    const int src = src_s[j];
    const int cw  = combo_s[j];
    const int tgt = tgt_s[j];
    const int r = cw >> 12, combo = cw & 0xFFF;

    const float4 q4 = *reinterpret_cast<const float4*>(&q0[(size_t)tgt*HD + h*32 + c4]);
    const f16x4 ka = *reinterpret_cast<const f16x4*>(&kA[((size_t)src*NR + r)*HD + h*32 + c4]);
    const f16x4 kc = *reinterpret_cast<const f16x4*>(&KcA[((size_t)combo*NR + r)*HD + h*32 + c4]);
    float v = q4.x*((float)ka[0]+(float)kc[0])
            + q4.y*((float)ka[1]+(float)kc[1])
            + q4.z*((float)ka[2]+(float)kc[2])
            + q4.w*((float)ka[3]+(float)kc[3]);
    v += __shfl_xor(v, 1); v += __shfl_xor(v, 2); v += __shfl_xor(v, 4);
    if ((lane & 7) == 0)
        s_arr[(size_t)j*NH + h] = v * relP[r*NH + h] * INV_SQRT_DK;
}

// ---------- node-parallel segment softmax (CSR) ----------
__global__ __launch_bounds__(256) void k_softmax(
    float* __restrict__ s_arr, const int* __restrict__ tgt_off, const int* __restrict__ eid_s,
    float* __restrict__ out_att, int store)
{
    const int idx = blockIdx.x*256 + threadIdx.x;
    if (idx >= NN*NH) return;
    const int n = idx >> 3, h = idx & 7;
    const int e0 = tgt_off[n], e1 = tgt_off[n+1];
    if (e0 == e1) return;
    float m = -INFINITY;
    for (int j = e0; j < e1; j++) m = fmaxf(m, s_arr[(size_t)j*NH + h]);
    float l = 0.f;
    for (int j = e0; j < e1; j++) l += __expf(s_arr[(size_t)j*NH + h] - m);
    const float inv = 1.f / l;
    for (int j = e0; j < e1; j++){
        const float a = __expf(s_arr[(size_t)j*NH + h] - m) * inv;
        s_arr[(size_t)j*NH + h] = a;
        if (store) out_att[(size_t)eid_s[j]*NH + h] = a;
    }
}

// ---------- aggregation (CSR, wave per node), gelu fused, f16 out ----------
__global__ __launch_bounds__(256) void k_agg(
    const _Float16* __restrict__ vM, const _Float16* __restrict__ VcM,
    const float* __restrict__ alpha,
    const int* __restrict__ tgt_off, const int* __restrict__ src_s, const int* __restrict__ combo_s,
    _Float16* __restrict__ agg)
{
    const int n = blockIdx.x*4 + (threadIdx.x >> 6);
    if (n >= NN) return;
    const int lane = threadIdx.x & 63;
    const int h = lane >> 3, c4 = (lane & 7) << 2;
    const int col = h*32 + c4;
    const int e0 = tgt_off[n], e1 = tgt_off[n+1];
    float a0=0.f, a1=0.f, a2=0.f, a3=0.f;
    for (int j = e0; j < e1; j++){
        const int src = src_s[j];
        const int cw  = combo_s[j];
        const int r = cw >> 12, combo = cw & 0xFFF;
        const float al = alpha[(size_t)j*NH + h];
        const f16x4 vm = *reinterpret_cast<const f16x4*>(&vM[((size_t)src*NR + r)*HD + col]);
        const f16x4 vc = *reinterpret_cast<const f16x4*>(&VcM[((size_t)combo*NR + r)*HD + col]);
        a0 = fmaf(al, (float)vm[0] + (float)vc[0], a0);
        a1 = fmaf(al, (float)vm[1] + (float)vc[1], a1);
        a2 = fmaf(al, (float)vm[2] + (float)vc[2], a2);
        a3 = fmaf(al, (float)vm[3] + (float)vc[3], a3);
    }
    f16x4 o;
    o[0] = (_Float16)(0.5f*a0*(1.f + erff(a0*0.70710678118654752f)));
    o[1] = (_Float16)(0.5f*a1*(1.f + erff(a1*0.70710678118654752f)));
    o[2] = (_Float16)(0.5f*a2*(1.f + erff(a2*0.70710678118654752f)));
    o[3] = (_Float16)(0.5f*a3*(1.f + erff(a3*0.70710678118654752f)));
    *reinterpret_cast<f16x4*>(&agg[(size_t)n*HD + col]) = o;
}

__global__ void k_copy(const float* __restrict__ s, float* __restrict__ d, int n){
    int i = blockIdx.x*256 + threadIdx.x;
    if (i < n) d[i] = s[i];
}

extern "C" void kernel_launch(void* const* d_in, const int* in_sizes, int n_in,
                              void* d_out, int out_size, void* d_ws, size_t ws_size,
                              hipStream_t stream)
{
    const float* node_feature = (const float*)d_in[0];
    const int*   node_type    = (const int*)d_in[1];
    const int*   edge_time    = (const int*)d_in[2];
    const int*   edge_index   = (const int*)d_in[3];
    const int*   edge_type    = (const int*)d_in[4];
    const float* adapt_W = (const float*)d_in[5];
    const float* adapt_b = (const float*)d_in[6];
    const float* k_W = (const float*)d_in[7];
    const float* k_b = (const float*)d_in[8];
    const float* q_W = (const float*)d_in[9];
    const float* q_b = (const float*)d_in[10];
    const float* v_W = (const float*)d_in[11];
    const float* v_b = (const float*)d_in[12];
    const float* a_W = (const float*)d_in[13];
    const float* a_b = (const float*)d_in[14];
    const float* rel_pri = (const float*)d_in[15];
    const float* rel_att = (const float*)d_in[16];
    const float* rel_msg = (const float*)d_in[17];
    const float* skip  = (const float*)d_in[18];
    const float* rte_W = (const float*)d_in[19];
    const float* rte_b = (const float*)d_in[20];
    const float* rte_emb = (const float*)d_in[21];

    char* wp = (char*)d_ws;
    auto alloc_f = [&](size_t n)->float*{ float* p=(float*)wp; wp += n*sizeof(float); return p; };
    auto alloc_i = [&](size_t n)->int*  { int*   p=(int*)wp;   wp += n*sizeof(int);   return p; };
    auto alloc_h = [&](size_t n)->_Float16*{ _Float16* p=(_Float16*)wp; wp += n*sizeof(_Float16); return p; };
    float* xA    = alloc_f((size_t)NN*HD);
    float* xB    = alloc_f((size_t)NN*HD);
    float* q0f   = alloc_f((size_t)NN*HD);
    _Float16* k0h = alloc_h((size_t)NN*HD);
    _Float16* v0h = alloc_h((size_t)NN*HD);
    _Float16* aggh= alloc_h((size_t)NN*HD);
    float* s_arr = alloc_f((size_t)NE*NH);
    float* rteP  = alloc_f((size_t)MAXL*HD);
    _Float16* Kch = alloc_h((size_t)MAXL*NT*HD);
    _Float16* Vch = alloc_h((size_t)MAXL*NT*HD);
    _Float16* kavm = alloc_h((size_t)NN*NR*HD);        // kA then reused for vM
    _Float16* kca  = alloc_h((size_t)MAXL*NT*NR*HD);   // KcA then reused for VcM
    _Float16* wF   = alloc_h((size_t)36*65536);        // adapt|q|k|v|a frag-major
    _Float16* relF = alloc_h((size_t)256*1024);        // att(128) | msg(128)
    int* nbucket = alloc_i(NN);
    int* nhist   = alloc_i(HBLK*NT);
    int* nbase   = alloc_i(HBLK*NT);
    int* noff    = alloc_i(8);
    int* tlist   = alloc_i(TMAX);
    int* tcount  = alloc_i(8);
    int* cnt     = alloc_i(NN);
    int* bsum    = alloc_i(SCB);
    int* bbase   = alloc_i(SCB);
    int* binCur  = alloc_i(NN);
    int* tgt_off = alloc_i(NN+1);
    int* src_s   = alloc_i(NE);
    int* combo_s = alloc_i(NE);
    int* eid_s   = alloc_i(NE);
    int* tgt_s   = alloc_i(NE);

    const _Float16* adaptF = wF;
    const _Float16* qF = wF + (size_t)4*65536;
    const _Float16* kF = wF + (size_t)12*65536;
    const _Float16* vF = wF + (size_t)20*65536;
    const _Float16* aF = wF + (size_t)28*65536;
    const _Float16* relAF = relF;
    const _Float16* relMF = relF + (size_t)128*1024;

    float* out_att = (float*)d_out;
    float* out_x   = (float*)d_out + (size_t)NE*NH;

    const dim3 gFold(FOLDN + FOLDC, NR);
    const int gE256 = (NE + 255)/256;
    const int gNH = (NN*HD + 255)/256;
    const int gSc = (NE + 3)/4;
    const int gSm = (NN*NH + 255)/256;
    const int gAg = (NN + 3)/4;

    // weight pre-pack to f16 fragment-major (2 merged launches)
    k_w2f16_big<<<dim3(64,36),256,0,stream>>>(adapt_W, q_W, k_W, v_W, a_W, wF);
    k_w2f16_rel<<<dim3(1,256),256,0,stream>>>(rel_att, rel_msg, relF);

    // node buckets (by type) + compact 32-row tile list
    k_nhist<<<HBLK,256,0,stream>>>(node_type, nhist);
    k_nscan<<<1,64,0,stream>>>(nhist, noff, nbase, tlist, tcount);
    k_nscatter<<<HBLK,256,0,stream>>>(node_type, nbase, nbucket);

    // edge CSR sorted by tgt
    k_zero_bins<<<SCB,256,0,stream>>>(cnt);
    k_csr_hist<<<gE256,256,0,stream>>>(edge_index, cnt);
    k_scan1<<<SCB,256,0,stream>>>(cnt, tgt_off, bsum);
    k_scan2<<<1,128,0,stream>>>(bsum, bbase, tgt_off);
    k_scan3<<<SCB,256,0,stream>>>(tgt_off, bbase, binCur);
    k_csr_scatter<<<gE256,256,0,stream>>>(edge_index, edge_type, edge_time, node_type,
                                          binCur, src_s, combo_s, eid_s, tgt_s);

    // adapt: x = tanh(node_feature @ adapt_W[t] + b)   (f32 in, f32 out)
    k_typed_mfma<<<TMAX,256,0,stream>>>(node_feature, nullptr, adaptF, nullptr, nullptr,
                                        adapt_b, nullptr, nullptr,
                                        xA, nullptr, nullptr,
                                        nbucket, noff, tlist, tcount, 1, 1, 0, nullptr, nullptr);

    const float* x_in = xA;
    float* x_out = xB;
    for (int l = 0; l < NL; l++){
        k_row_gemm<<<MAXL,256,0,stream>>>(rte_emb, rte_W + (size_t)l*HD*HD,
                                          rte_b + (size_t)l*HD, rteP);
        k_row_gemm2<<<dim3(MAXL,NT,2),256,0,stream>>>(rteP, k_W + (size_t)l*NT*HD*HD,
                                                      v_W + (size_t)l*NT*HD*HD, Kch, Vch);
        // fused Q/K/V node-level GEMM: q -> f32, k/v -> f16
        k_typed_mfma<<<TMAX,256,0,stream>>>(x_in, nullptr,
                                            qF + (size_t)l*NT*HD*HD, kF + (size_t)l*NT*HD*HD, vF + (size_t)l*NT*HD*HD,
                                            q_b + (size_t)l*NT*HD,  k_b + (size_t)l*NT*HD,  v_b + (size_t)l*NT*HD,
                                            q0f, k0h, v0h,
                                            nbucket, noff, tlist, tcount, 3, 0, 6, nullptr, nullptr);
        // fold rel_att into node-level + combo-level tables (merged)
        k_fold_mfma<<<gFold,256,0,stream>>>(k0h, Kch, relAF + (size_t)l*NR*NH*1024, kavm, kca);
        // scores + softmax
        k_score<<<gSc,256,0,stream>>>(q0f, kavm, kca, rel_pri + (size_t)l*NR*NH,
                                      src_s, combo_s, tgt_s, s_arr);
        const int store_s = (l == NL-1) ? 1 : 0;
        k_softmax<<<gSm,256,0,stream>>>(s_arr, tgt_off, eid_s, out_att, store_s);
        // fold rel_msg (merged), then aggregate (+gelu, f16 out)
        k_fold_mfma<<<gFold,256,0,stream>>>(v0h, Vch, relMF + (size_t)l*NR*NH*1024, kavm, kca);
        k_agg<<<gAg,256,0,stream>>>(kavm, kca, s_arr, tgt_off, src_s, combo_s, aggh);
        // output transform + skip (f16 in, f32 out)
        k_typed_mfma<<<TMAX,256,0,stream>>>(nullptr, aggh,
                                            aF + (size_t)l*NT*HD*HD, nullptr, nullptr,
                                            a_b + (size_t)l*NT*HD, nullptr, nullptr,
                                            x_out, nullptr, nullptr,
                                            nbucket, noff, tlist, tcount, 1, 2, 0, skip + (size_t)l*NT, x_in);
        float* tmp = (float*)x_in; x_in = x_out; x_out = tmp;
    }
    k_copy<<<gNH,256,0,stream>>>(x_in, out_x, NN*HD);
}

// Round 19
// 597.344 us; speedup vs baseline: 1.1343x; 1.0079x over previous
//
#include <hip/hip_runtime.h>
#include <hip/hip_fp16.h>

#define NN    20000
#define NE    150000
#define HD    256
#define NT    4
#define NR    8
#define NH    8
#define DKq   32
#define NL    2
#define MAXL  240
#define HBLK  256
#define SCB   ((NN + 255)/256)
#define TMAX  632
#define FOLDN 79
#define FOLDC 15
#define INV_SQRT_DK 0.17677669529663687f

typedef _Float16 f16x4 __attribute__((ext_vector_type(4)));
typedef float    f32x4v __attribute__((ext_vector_type(4)));

// ---------- node bucketing (by type) + compact 32-row tile list ----------
__global__ __launch_bounds__(256) void k_nhist(const int* __restrict__ ntype, int* __restrict__ nhist)
{
    __shared__ int h[NT];
    const int tid = threadIdx.x, b = blockIdx.x;
    if (tid < NT) h[tid] = 0;
    __syncthreads();
    const int cn = (NN + HBLK-1)/HBLK;
    const int nEnd = min((b+1)*cn, NN);
    for (int i = b*cn + tid; i < nEnd; i += 256) atomicAdd(&h[ntype[i]], 1);
    __syncthreads();
    if (tid < NT) nhist[b*NT + tid] = h[tid];
}
__global__ void k_nscan(const int* __restrict__ nhist, int* __restrict__ noff, int* __restrict__ nbase,
                        int* __restrict__ tlist, int* __restrict__ tcount)
{
    __shared__ int tot[NT];
    const int tid = threadIdx.x;
    if (tid < NT){
        int s = 0;
        for (int b = 0; b < HBLK; b++) s += nhist[b*NT + tid];
        tot[tid] = s;
    }
    __syncthreads();
    if (tid == 0){ noff[0]=0; for (int t=0;t<NT;t++) noff[t+1]=noff[t]+tot[t]; }
    if (tid < NT){
        int base = 0; for (int t=0;t<tid;t++) base += tot[t];
        int run = 0;
        for (int b=0;b<HBLK;b++){ nbase[b*NT+tid] = base + run; run += nhist[b*NT+tid]; }
    }
    __syncthreads();
    if (tid == 0){
        int c = 0;
        for (int t = 0; t < NT; t++){
            const int ntile = (tot[t] + 31) >> 5;
            for (int rt = 0; rt < ntile; rt++) tlist[c++] = (t << 20) | rt;
        }
        *tcount = c;
    }
}
__global__ __launch_bounds__(256) void k_nscatter(const int* __restrict__ ntype,
    const int* __restrict__ nbase, int* __restrict__ nbucket)
{
    __shared__ int cur[NT];
    const int tid = threadIdx.x, b = blockIdx.x;
    if (tid < NT) cur[tid] = nbase[b*NT + tid];
    __syncthreads();
    const int cn = (NN + HBLK-1)/HBLK;
    const int nEnd = min((b+1)*cn, NN);
    for (int i = b*cn + tid; i < nEnd; i += 256)
        nbucket[atomicAdd(&cur[ntype[i]], 1)] = i;
}

// ---------- edge CSR build: sort by tgt ----------
__global__ void k_zero_bins(int* __restrict__ cnt){
    int i = blockIdx.x*256 + threadIdx.x;
    if (i < NN) cnt[i] = 0;
}
__global__ void k_csr_hist(const int* __restrict__ ei, int* __restrict__ cnt){
    int e = blockIdx.x*256 + threadIdx.x;
    if (e >= NE) return;
    atomicAdd(&cnt[ei[NE+e]], 1);
}
__global__ __launch_bounds__(256) void k_scan1(const int* __restrict__ cnt,
    int* __restrict__ tgt_off, int* __restrict__ bsum)
{
    __shared__ int sh[256];
    const int t = threadIdx.x, b = blockIdx.x;
    const int i = b*256 + t;
    const int v = (i < NN) ? cnt[i] : 0;
    sh[t] = v;
    __syncthreads();
    #pragma unroll
    for (int d = 1; d < 256; d <<= 1){
        const int u = (t >= d) ? sh[t-d] : 0;
        __syncthreads();
        sh[t] += u;
        __syncthreads();
    }
    if (i < NN) tgt_off[i] = sh[t] - v;
    if (t == 255) bsum[b] = sh[255];
}
__global__ __launch_bounds__(128) void k_scan2(const int* __restrict__ bsum,
    int* __restrict__ bbase, int* __restrict__ tgt_off)
{
    __shared__ int sh[128];
    const int t = threadIdx.x;
    const int v = (t < SCB) ? bsum[t] : 0;
    sh[t] = v;
    __syncthreads();
    #pragma unroll
    for (int d = 1; d < 128; d <<= 1){
        const int u = (t >= d) ? sh[t-d] : 0;
        __syncthreads();
        sh[t] += u;
        __syncthreads();
    }
    if (t < SCB) bbase[t] = sh[t] - v;
    if (t == 0) tgt_off[NN] = NE;
}
__global__ __launch_bounds__(256) void k_scan3(int* __restrict__ tgt_off,
    const int* __restrict__ bbase, int* __restrict__ binCur)
{
    const int i = blockIdx.x*256 + threadIdx.x;
    if (i >= NN) return;
    const int o = tgt_off[i] + bbase[blockIdx.x];
    tgt_off[i] = o;
    binCur[i] = o;
}
__global__ void k_csr_scatter(const int* __restrict__ ei, const int* __restrict__ etype,
    const int* __restrict__ etime, const int* __restrict__ ntype,
    int* __restrict__ binCur, int* __restrict__ src_s, int* __restrict__ combo_s,
    int* __restrict__ eid_s, int* __restrict__ tgt_s)
{
    int e = blockIdx.x*256 + threadIdx.x;
    if (e >= NE) return;
    const int tgt = ei[NE+e], r = etype[e], src = ei[e];
    const int pos = atomicAdd(&binCur[tgt], 1);
    src_s[pos] = src;
    combo_s[pos] = (etime[e]*NT + ntype[src]) | (r << 12);
    eid_s[pos] = e;
    tgt_s[pos] = tgt;
}

// ---------- weight pre-pack (merged): 36 big 256x256 mats -> frag-major f16 ----------
__global__ __launch_bounds__(256) void k_w2f16_big(
    const float* __restrict__ adaptW, const float* __restrict__ qW, const float* __restrict__ kW,
    const float* __restrict__ vW, const float* __restrict__ aW, _Float16* __restrict__ out)
{
    const int y = blockIdx.y;
    const float* src; int m;
    if (y < 4){ src = adaptW; m = y; }
    else if (y < 12){ src = qW; m = y-4; }
    else if (y < 20){ src = kW; m = y-12; }
    else if (y < 28){ src = vW; m = y-20; }
    else { src = aW; m = y-28; }
    const float* ip = src + (size_t)m*65536;
    _Float16* op = out + (size_t)y*65536;
    const int tid4 = blockIdx.x*256 + threadIdx.x;
    const int k4 = tid4 >> 8, c = tid4 & 255;
    f16x4 hv;
    #pragma unroll
    for (int j = 0; j < 4; j++)
        hv[j] = (_Float16)ip[(size_t)(((k4*4 + j) << 8) + c)];
    *reinterpret_cast<f16x4*>(&op[(size_t)tid4 * 4]) = hv;
}
// 256 rel 32x32 mats (att then msg) -> frag-major f16
__global__ __launch_bounds__(256) void k_w2f16_rel(
    const float* __restrict__ attW, const float* __restrict__ msgW, _Float16* __restrict__ out)
{
    const int y = blockIdx.y;
    const float* ip = (y < 128) ? (attW + (size_t)y*1024) : (msgW + (size_t)(y-128)*1024);
    _Float16* op = out + (size_t)y*1024;
    const int tid4 = threadIdx.x;
    const int k4 = tid4 >> 5, c = tid4 & 31;
    f16x4 hv;
    #pragma unroll
    for (int j = 0; j < 4; j++)
        hv[j] = (_Float16)ip[(size_t)(((k4*4 + j) << 5) + c)];
    *reinterpret_cast<f16x4*>(&op[(size_t)tid4 * 4]) = hv;
}

// ---------- fused typed MFMA GEMM: proc0 (act) optionally chained into q/k/v ----------
// 32-row tiles via compact list. proc0 computes act(in@Wa+ba) (mode 0/1/2); if Wq!=null,
// its output tile is written back into LDS (f16) and q/k/v procs consume it directly.
// ohmask: bit0 oa, bit1 oq, bit2 ok, bit3 ov -> f16 output.
__global__ __launch_bounds__(256) void k_typed_fused(
    const float* __restrict__ inF, const _Float16* __restrict__ inH,
    const _Float16* __restrict__ Wa, const float* __restrict__ ba, void* __restrict__ oa,
    const _Float16* __restrict__ Wq, const float* __restrict__ bq, void* __restrict__ oq,
    const _Float16* __restrict__ Wk, const float* __restrict__ bk, void* __restrict__ ok_,
    const _Float16* __restrict__ Wv, const float* __restrict__ bv, void* __restrict__ ov,
    const int* __restrict__ nbucket, const int* __restrict__ noff,
    const int* __restrict__ tlist, const int* __restrict__ tcount,
    int mode, int ohmask, const float* __restrict__ skipv, const float* __restrict__ xold)
{
    if ((int)blockIdx.x >= *tcount) return;
    const int ent = tlist[blockIdx.x];
    const int t = ent >> 20, rowTile = ent & 0xFFFFF;
    const int start = noff[t], cnt = noff[t+1] - start;

    const int tid = threadIdx.x;
    const int w = tid >> 6, lane = tid & 63;
    const int lrow = lane & 15, lgrp = lane >> 4;

    __shared__ _Float16 Al[32][260];
    __shared__ int nid[32];

    if (tid < 32){
        const int gr = rowTile*32 + tid;
        nid[tid] = (gr < cnt) ? nbucket[start + gr] : -1;
    }
    __syncthreads();

    // stage A once: 8 threads per row
    {
        const int r = tid >> 3;
        const int arow = nid[r];
        if (inH){
            const _Float16* ap = (arow >= 0) ? (inH + (size_t)arow*HD) : nullptr;
            #pragma unroll
            for (int j = 0; j < 8; j++){
                const int f4 = (tid & 7) + j*8;
                f16x4 hv = {0,0,0,0};
                if (ap) hv = *reinterpret_cast<const f16x4*>(ap + f4*4);
                *reinterpret_cast<f16x4*>(&Al[r][f4*4]) = hv;
            }
        } else {
            const float* ap = (arow >= 0) ? (inF + (size_t)arow*HD) : nullptr;
            #pragma unroll
            for (int j = 0; j < 8; j++){
                const int f4 = (tid & 7) + j*8;
                float4 v = make_float4(0.f,0.f,0.f,0.f);
                if (ap) v = *reinterpret_cast<const float4*>(ap + f4*4);
                f16x4 hv;
                hv[0]=(_Float16)v.x; hv[1]=(_Float16)v.y; hv[2]=(_Float16)v.z; hv[3]=(_Float16)v.w;
                *reinterpret_cast<f16x4*>(&Al[r][f4*4]) = hv;
            }
        }
    }
    __syncthreads();

    float sk = 0.f;
    if (mode == 2) sk = 1.f/(1.f + __expf(-skipv[t]));

    const bool chain = (Wq != nullptr);

    auto proc = [&](const _Float16* Wb, const float* bb, void* out, int oh, int md, bool cw){
        const _Float16* W = Wb + (size_t)t*HD*HD;
        const float* bias = bb + (size_t)t*HD;
        f32x4v acc[4][2];
        #pragma unroll
        for (int cs = 0; cs < 4; cs++){
            acc[cs][0] = (f32x4v){0.f,0.f,0.f,0.f};
            acc[cs][1] = (f32x4v){0.f,0.f,0.f,0.f};
        }
        #pragma unroll 4
        for (int kc = 0; kc < 16; kc++){
            f16x4 bf[4];
            #pragma unroll
            for (int cs = 0; cs < 4; cs++)
                bf[cs] = *reinterpret_cast<const f16x4*>(
                    &W[(size_t)((kc*4 + lgrp)*HD + w*64 + cs*16 + lrow)*4]);
            const f16x4 af0 = *reinterpret_cast<const f16x4*>(&Al[lrow][kc*16 + lgrp*4]);
            const f16x4 af1 = *reinterpret_cast<const f16x4*>(&Al[16 + lrow][kc*16 + lgrp*4]);
            #pragma unroll
            for (int cs = 0; cs < 4; cs++){
                acc[cs][0] = __builtin_amdgcn_mfma_f32_16x16x16f16(af0, bf[cs], acc[cs][0], 0,0,0);
                acc[cs][1] = __builtin_amdgcn_mfma_f32_16x16x16f16(af1, bf[cs], acc[cs][1], 0,0,0);
            }
        }
        if (cw) __syncthreads();   // all waves done reading Al before overwrite
        #pragma unroll
        for (int cs = 0; cs < 4; cs++){
            const int col = w*64 + cs*16 + lrow;
            const float bcol = bias[col];
            #pragma unroll
            for (int rt = 0; rt < 2; rt++){
                #pragma unroll
                for (int i = 0; i < 4; i++){
                    const int lr = rt*16 + lgrp*4 + i;
                    const int gr = rowTile*32 + lr;
                    if (gr >= cnt) continue;
                    const int node = nid[lr];
                    float v = acc[cs][rt][i] + bcol;
                    if (md == 1) v = tanhf(v);
                    else if (md == 2){
                        const float xo = xold[(size_t)node*HD + col];
                        v = v*sk + xo*(1.f - sk);
                    }
                    if (oh) ((_Float16*)out)[(size_t)node*HD + col] = (_Float16)v;
                    else    ((float*)out)[(size_t)node*HD + col] = v;
                    if (cw) Al[lr][col] = (_Float16)v;
                }
            }
        }
        if (cw) __syncthreads();   // new x tile visible to q/k/v procs
    };

    proc(Wa, ba, oa, ohmask & 1, mode, chain);
    if (chain){
        proc(Wq, bq, oq, (ohmask >> 1) & 1, 0, false);
        proc(Wk, bk, ok_, (ohmask >> 2) & 1, 0, false);
        proc(Wv, bv, ov, (ohmask >> 3) & 1, 0, false);
    }
}

// ---------- small row GEMM: rteP = rte_emb @ rte_W + rte_b (f32 out) ----------
__global__ __launch_bounds__(256) void k_row_gemm(
    const float* __restrict__ A, const float* __restrict__ W, const float* __restrict__ bias,
    float* __restrict__ C)
{
    const int row = blockIdx.x, d = threadIdx.x;
    __shared__ float ar[HD];
    ar[d] = A[(size_t)row*HD + d];
    __syncthreads();
    float acc = bias[d];
    #pragma unroll 8
    for (int k=0;k<HD;k++) acc = fmaf(ar[k], W[(size_t)k*HD + d], acc);
    C[(size_t)row*HD + d] = acc;
}
// merged Kc/Vc: z=0 -> k_W->Kch ; z=1 -> v_W->Vch   (f16 out)
__global__ __launch_bounds__(256) void k_row_gemm2(
    const float* __restrict__ A, const float* __restrict__ kWb, const float* __restrict__ vWb,
    _Float16* __restrict__ Kc, _Float16* __restrict__ Vc)
{
    const int row = blockIdx.x, ty = blockIdx.y, d = threadIdx.x;
    const float* W = ((blockIdx.z == 0) ? kWb : vWb) + (size_t)ty*HD*HD;
    _Float16* C = (blockIdx.z == 0) ? Kc : Vc;
    __shared__ float ar[HD];
    ar[d] = A[(size_t)row*HD + d];
    __syncthreads();
    float acc = 0.f;
    #pragma unroll 8
    for (int k=0;k<HD;k++) acc = fmaf(ar[k], W[(size_t)k*HD + d], acc);
    C[(size_t)row*(NT*HD) + ty*HD + d] = (_Float16)acc;
}

// ---------- MFMA fold (generic): OUT[m][r][*] = IN[m] @ MAT[r], grid (nbx, NR) ----------
__global__ __launch_bounds__(256) void k_fold_mfma(
    const _Float16* __restrict__ IN, const _Float16* __restrict__ MATF,
    _Float16* __restrict__ OUT, int M, int nbx)
{
    const int r = blockIdx.y;
    const int lane = threadIdx.x & 63, w = threadIdx.x >> 6;
    const int lrow = lane & 15, lgrp = lane >> 4;
    f16x4 b[NH][2][2];
    const _Float16* Mr = MATF + (size_t)r*NH*1024;
    #pragma unroll
    for (int h = 0; h < NH; h++)
      #pragma unroll
      for (int kb = 0; kb < 2; kb++)
        #pragma unroll
        for (int hf = 0; hf < 2; hf++)
            b[h][kb][hf] = *reinterpret_cast<const f16x4*>(
                &Mr[(size_t)h*1024 + (size_t)(((kb*4 + lgrp)*32) + hf*16 + lrow)*4]);
    const int ntiles = M >> 4;
    for (int t = (int)blockIdx.x*4 + w; t < ntiles; t += nbx*4){
        const int row0 = t*16;
        const _Float16* inrow = IN + (size_t)(row0 + lrow)*HD;
        f16x4 a[NH][2];
        #pragma unroll
        for (int h = 0; h < NH; h++)
          #pragma unroll
          for (int kb = 0; kb < 2; kb++)
              a[h][kb] = *reinterpret_cast<const f16x4*>(&inrow[h*32 + kb*16 + lgrp*4]);
        #pragma unroll
        for (int h = 0; h < NH; h++){
          #pragma unroll
          for (int hf = 0; hf < 2; hf++){
              f32x4v acc = {0.f,0.f,0.f,0.f};
              acc = __builtin_amdgcn_mfma_f32_16x16x16f16(a[h][0], b[h][0][hf], acc, 0,0,0);
              acc = __builtin_amdgcn_mfma_f32_16x16x16f16(a[h][1], b[h][1][hf], acc, 0,0,0);
              #pragma unroll
              for (int i = 0; i < 4; i++){
                  const int rr = lgrp*4 + i;
                  OUT[((size_t)(row0+rr)*NR + r)*HD + h*32 + hf*16 + lrow] = (_Float16)acc[i];
              }
          }
        }
    }
}

// ---------- edge scores (streaming, wave per edge; f32 q for softmax precision) ----------
__global__ __launch_bounds__(256) void k_score(
    const float* __restrict__ q0, const _Float16* __restrict__ kA, const _Float16* __restrict__ KcA,
    const float* __restrict__ relP,
    const int* __restrict__ src_s, const int* __restrict__ combo_s, const int* __restrict__ tgt_s,
    float* __restrict__ s_arr)
{
    const int j = blockIdx.x*4 + (threadIdx.x >> 6);
    if (j >= NE) return;
    const int lane = threadIdx.x & 63;
    const int h = lane >> 3, c4 = (lane & 7) << 2;
    const int src = src_s[j];
    const int cw  = combo_s[j];
    const int tgt = tgt_s[j];
    const int r = cw >> 12, combo = cw & 0xFFF;

    const float4 q4 = *reinterpret_cast<const float4*>(&q0[(size_t)tgt*HD + h*32 + c4]);
    const f16x4 ka = *reinterpret_cast<const f16x4*>(&kA[((size_t)src*NR + r)*HD + h*32 + c4]);
    const f16x4 kc = *reinterpret_cast<const f16x4*>(&KcA[((size_t)combo*NR + r)*HD + h*32 + c4]);
    float v = q4.x*((float)ka[0]+(float)kc[0])
            + q4.y*((float)ka[1]+(float)kc[1])
            + q4.z*((float)ka[2]+(float)kc[2])
            + q4.w*((float)ka[3]+(float)kc[3]);
    v += __shfl_xor(v, 1); v += __shfl_xor(v, 2); v += __shfl_xor(v, 4);
    if ((lane & 7) == 0)
        s_arr[(size_t)j*NH + h] = v * relP[r*NH + h] * INV_SQRT_DK;
}

// ---------- node-parallel segment softmax (CSR) ----------
__global__ __launch_bounds__(256) void k_softmax(
    float* __restrict__ s_arr, const int* __restrict__ tgt_off, const int* __restrict__ eid_s,
    float* __restrict__ out_att, int store)
{
    const int idx = blockIdx.x*256 + threadIdx.x;
    if (idx >= NN*NH) return;
    const int n = idx >> 3, h = idx & 7;
    const int e0 = tgt_off[n], e1 = tgt_off[n+1];
    if (e0 == e1) return;
    float m = -INFINITY;
    for (int j = e0; j < e1; j++) m = fmaxf(m, s_arr[(size_t)j*NH + h]);
    float l = 0.f;
    for (int j = e0; j < e1; j++) l += __expf(s_arr[(size_t)j*NH + h] - m);
    const float inv = 1.f / l;
    for (int j = e0; j < e1; j++){
        const float a = __expf(s_arr[(size_t)j*NH + h] - m) * inv;
        s_arr[(size_t)j*NH + h] = a;
        if (store) out_att[(size_t)eid_s[j]*NH + h] = a;
    }
}

// ---------- aggregation (CSR, wave per node), gelu fused, f16 out ----------
__global__ __launch_bounds__(256) void k_agg(
    const _Float16* __restrict__ vM, const _Float16* __restrict__ VcM,
    const float* __restrict__ alpha,
    const int* __restrict__ tgt_off, const int* __restrict__ src_s, const int* __restrict__ combo_s,
    _Float16* __restrict__ agg)
{
    const int n = blockIdx.x*4 + (threadIdx.x >> 6);
    if (n >= NN) return;
    const int lane = threadIdx.x & 63;
    const int h = lane >> 3, c4 = (lane & 7) << 2;
    const int col = h*32 + c4;
    const int e0 = tgt_off[n], e1 = tgt_off[n+1];
    float a0=0.f, a1=0.f, a2=0.f, a3=0.f;
    for (int j = e0; j < e1; j++){
        const int src = src_s[j];
        const int cw  = combo_s[j];
        const int r = cw >> 12, combo = cw & 0xFFF;
        const float al = alpha[(size_t)j*NH + h];
        const f16x4 vm = *reinterpret_cast<const f16x4*>(&vM[((size_t)src*NR + r)*HD + col]);
        const f16x4 vc = *reinterpret_cast<const f16x4*>(&VcM[((size_t)combo*NR + r)*HD + col]);
        a0 = fmaf(al, (float)vm[0] + (float)vc[0], a0);
        a1 = fmaf(al, (float)vm[1] + (float)vc[1], a1);
        a2 = fmaf(al, (float)vm[2] + (float)vc[2], a2);
        a3 = fmaf(al, (float)vm[3] + (float)vc[3], a3);
    }
    f16x4 o;
    o[0] = (_Float16)(0.5f*a0*(1.f + erff(a0*0.70710678118654752f)));
    o[1] = (_Float16)(0.5f*a1*(1.f + erff(a1*0.70710678118654752f)));
    o[2] = (_Float16)(0.5f*a2*(1.f + erff(a2*0.70710678118654752f)));
    o[3] = (_Float16)(0.5f*a3*(1.f + erff(a3*0.70710678118654752f)));
    *reinterpret_cast<f16x4*>(&agg[(size_t)n*HD + col]) = o;
}

extern "C" void kernel_launch(void* const* d_in, const int* in_sizes, int n_in,
                              void* d_out, int out_size, void* d_ws, size_t ws_size,
                              hipStream_t stream)
{
    const float* node_feature = (const float*)d_in[0];
    const int*   node_type    = (const int*)d_in[1];
    const int*   edge_time    = (const int*)d_in[2];
    const int*   edge_index   = (const int*)d_in[3];
    const int*   edge_type    = (const int*)d_in[4];
    const float* adapt_W = (const float*)d_in[5];
    const float* adapt_b = (const float*)d_in[6];
    const float* k_W = (const float*)d_in[7];
    const float* k_b = (const float*)d_in[8];
    const float* q_W = (const float*)d_in[9];
    const float* q_b = (const float*)d_in[10];
    const float* v_W = (const float*)d_in[11];
    const float* v_b = (const float*)d_in[12];
    const float* a_W = (const float*)d_in[13];
    const float* a_b = (const float*)d_in[14];
    const float* rel_pri = (const float*)d_in[15];
    const float* rel_att = (const float*)d_in[16];
    const float* rel_msg = (const float*)d_in[17];
    const float* skip  = (const float*)d_in[18];
    const float* rte_W = (const float*)d_in[19];
    const float* rte_b = (const float*)d_in[20];
    const float* rte_emb = (const float*)d_in[21];

    char* wp = (char*)d_ws;
    auto alloc_f = [&](size_t n)->float*{ float* p=(float*)wp; wp += n*sizeof(float); return p; };
    auto alloc_i = [&](size_t n)->int*  { int*   p=(int*)wp;   wp += n*sizeof(int);   return p; };
    auto alloc_h = [&](size_t n)->_Float16*{ _Float16* p=(_Float16*)wp; wp += n*sizeof(_Float16); return p; };
    float* xA    = alloc_f((size_t)NN*HD);
    float* xB    = alloc_f((size_t)NN*HD);
    float* q0f   = alloc_f((size_t)NN*HD);
    _Float16* k0h = alloc_h((size_t)NN*HD);
    _Float16* v0h = alloc_h((size_t)NN*HD);
    _Float16* aggh= alloc_h((size_t)NN*HD);
    float* s_arr = alloc_f((size_t)NE*NH);
    float* rteP  = alloc_f((size_t)MAXL*HD);
    _Float16* Kch = alloc_h((size_t)MAXL*NT*HD);
    _Float16* Vch = alloc_h((size_t)MAXL*NT*HD);
    _Float16* kavm = alloc_h((size_t)NN*NR*HD);            // kA then reused for vM
    _Float16* kcaA0 = alloc_h((size_t)MAXL*NT*NR*HD);
    _Float16* kcaA1 = alloc_h((size_t)MAXL*NT*NR*HD);
    _Float16* kcaM0 = alloc_h((size_t)MAXL*NT*NR*HD);
    _Float16* kcaM1 = alloc_h((size_t)MAXL*NT*NR*HD);
    _Float16* wF   = alloc_h((size_t)36*65536);            // adapt|q|k|v|a frag-major
    _Float16* relF = alloc_h((size_t)256*1024);            // att(128) | msg(128)
    int* nbucket = alloc_i(NN);
    int* nhist   = alloc_i(HBLK*NT);
    int* nbase   = alloc_i(HBLK*NT);
    int* noff    = alloc_i(8);
    int* tlist   = alloc_i(TMAX);
    int* tcount  = alloc_i(8);
    int* cnt     = alloc_i(NN);
    int* bsum    = alloc_i(SCB);
    int* bbase   = alloc_i(SCB);
    int* binCur  = alloc_i(NN);
    int* tgt_off = alloc_i(NN+1);
    int* src_s   = alloc_i(NE);
    int* combo_s = alloc_i(NE);
    int* eid_s   = alloc_i(NE);
    int* tgt_s   = alloc_i(NE);

    const _Float16* adaptF = wF;
    const _Float16* qF = wF + (size_t)4*65536;
    const _Float16* kF = wF + (size_t)12*65536;
    const _Float16* vF = wF + (size_t)20*65536;
    const _Float16* aF = wF + (size_t)28*65536;
    const _Float16* relAF = relF;
    const _Float16* relMF = relF + (size_t)128*1024;

    float* out_att = (float*)d_out;
    float* out_x   = (float*)d_out + (size_t)NE*NH;

    const dim3 gFoldN(FOLDN, NR);
    const dim3 gFoldC(FOLDC, NR);
    const int gE256 = (NE + 255)/256;
    const int gSc = (NE + 3)/4;
    const int gSm = (NN*NH + 255)/256;
    const int gAg = (NN + 3)/4;

    // weight pre-pack to f16 fragment-major
    k_w2f16_big<<<dim3(64,36),256,0,stream>>>(adapt_W, q_W, k_W, v_W, a_W, wF);
    k_w2f16_rel<<<dim3(1,256),256,0,stream>>>(rel_att, rel_msg, relF);

    // node buckets (by type) + compact 32-row tile list
    k_nhist<<<HBLK,256,0,stream>>>(node_type, nhist);
    k_nscan<<<1,64,0,stream>>>(nhist, noff, nbase, tlist, tcount);
    k_nscatter<<<HBLK,256,0,stream>>>(node_type, nbase, nbucket);

    // edge CSR sorted by tgt
    k_zero_bins<<<SCB,256,0,stream>>>(cnt);
    k_csr_hist<<<gE256,256,0,stream>>>(edge_index, cnt);
    k_scan1<<<SCB,256,0,stream>>>(cnt, tgt_off, bsum);
    k_scan2<<<1,128,0,stream>>>(bsum, bbase, tgt_off);
    k_scan3<<<SCB,256,0,stream>>>(tgt_off, bbase, binCur);
    k_csr_scatter<<<gE256,256,0,stream>>>(edge_index, edge_type, edge_time, node_type,
                                          binCur, src_s, combo_s, eid_s, tgt_s);

    // preamble: layer-invariant combo tables for both layers
    {
        // layer 0
        k_row_gemm<<<MAXL,256,0,stream>>>(rte_emb, rte_W, rte_b, rteP);
        k_row_gemm2<<<dim3(MAXL,NT,2),256,0,stream>>>(rteP, k_W, v_W, Kch, Vch);
        k_fold_mfma<<<gFoldC,256,0,stream>>>(Kch, relAF, kcaA0, MAXL*NT, FOLDC);
        k_fold_mfma<<<gFoldC,256,0,stream>>>(Vch, relMF, kcaM0, MAXL*NT, FOLDC);
        // layer 1
        k_row_gemm<<<MAXL,256,0,stream>>>(rte_emb, rte_W + (size_t)HD*HD, rte_b + HD, rteP);
        k_row_gemm2<<<dim3(MAXL,NT,2),256,0,stream>>>(rteP, k_W + (size_t)NT*HD*HD,
                                                      v_W + (size_t)NT*HD*HD, Kch, Vch);
        k_fold_mfma<<<gFoldC,256,0,stream>>>(Kch, relAF + (size_t)NR*NH*1024, kcaA1, MAXL*NT, FOLDC);
        k_fold_mfma<<<gFoldC,256,0,stream>>>(Vch, relMF + (size_t)NR*NH*1024, kcaM1, MAXL*NT, FOLDC);
    }

    // F0: adapt + QKV(l=0) fused (f32 in; x->xA f32; q f32, k/v f16)
    k_typed_fused<<<TMAX,256,0,stream>>>(node_feature, nullptr,
                                         adaptF, adapt_b, xA,
                                         qF, q_b, q0f,
                                         kF, k_b, k0h,
                                         vF, v_b, v0h,
                                         nbucket, noff, tlist, tcount,
                                         1, 12, nullptr, nullptr);

    for (int l = 0; l < NL; l++){
        const _Float16* rAF = relAF + (size_t)l*NR*NH*1024;
        const _Float16* rMF = relMF + (size_t)l*NR*NH*1024;
        const _Float16* kcaA = (l == 0) ? kcaA0 : kcaA1;
        const _Float16* kcaM = (l == 0) ? kcaM0 : kcaM1;
        // fold rel_att into node table
        k_fold_mfma<<<gFoldN,256,0,stream>>>(k0h, rAF, kavm, NN, FOLDN);
        // scores + softmax
        k_score<<<gSc,256,0,stream>>>(q0f, kavm, kcaA, rel_pri + (size_t)l*NR*NH,
                                      src_s, combo_s, tgt_s, s_arr);
        const int store_s = (l == NL-1) ? 1 : 0;
        k_softmax<<<gSm,256,0,stream>>>(s_arr, tgt_off, eid_s, out_att, store_s);
        // fold rel_msg into node table, then aggregate (+gelu)
        k_fold_mfma<<<gFoldN,256,0,stream>>>(v0h, rMF, kavm, NN, FOLDN);
        k_agg<<<gAg,256,0,stream>>>(kavm, kcaM, s_arr, tgt_off, src_s, combo_s, aggh);
        // aW(l) (+ chained QKV(l+1) if not last layer)
        if (l == 0){
            k_typed_fused<<<TMAX,256,0,stream>>>(nullptr, aggh,
                                                 aF, a_b, xB,
                                                 qF + (size_t)NT*HD*HD, q_b + (size_t)NT*HD, q0f,
                                                 kF + (size_t)NT*HD*HD, k_b + (size_t)NT*HD, k0h,
                                                 vF + (size_t)NT*HD*HD, v_b + (size_t)NT*HD, v0h,
                                                 nbucket, noff, tlist, tcount,
                                                 2, 12, skip, xA);
        } else {
            k_typed_fused<<<TMAX,256,0,stream>>>(nullptr, aggh,
                                                 aF + (size_t)NT*HD*HD, a_b + (size_t)NT*HD, out_x,
                                                 nullptr, nullptr, nullptr,
                                                 nullptr, nullptr, nullptr,
                                                 nullptr, nullptr, nullptr,
                                                 nbucket, noff, tlist, tcount,
                                                 2, 0, skip + NT, xB);
        }
    }
}